// Round 2
// baseline (691.825 us; speedup 1.0000x reference)
//
#include <hip/hip_runtime.h>
#include <hip/hip_bf16.h>

typedef unsigned short u16;
typedef u16 u16x8 __attribute__((ext_vector_type(8)));
typedef float f32x8 __attribute__((ext_vector_type(8)));

#define IN_DIM 1024
#define H_DIM  2048
#define V_DIM  50257
#define NEG_BIG (-1e30f)

__device__ __forceinline__ float bf2f(u16 u) {
    union { unsigned int i; float f; } v;
    v.i = ((unsigned int)u) << 16;
    return v.f;
}

__device__ __forceinline__ u16 f2bf(float f) {
    union { float f; unsigned int i; } v;
    v.f = f;
    unsigned int i = v.i;
    i += 0x7fffu + ((i >> 16) & 1u);   // round-to-nearest-even
    return (u16)(i >> 16);
}

__device__ __forceinline__ float wave_reduce_sum(float v) {
    #pragma unroll
    for (int off = 32; off > 0; off >>= 1) v += __shfl_down(v, off, 64);
    return v;
}

__device__ __forceinline__ float sigmoidf(float x) { return 1.f / (1.f + __expf(-x)); }

__device__ __forceinline__ float ld_scalar(const void* p, int i, bool bf) {
    return bf ? bf2f(((const u16*)p)[i]) : ((const float*)p)[i];
}

__device__ __forceinline__ const void* row_ptr(const void* W, size_t row, int n, bool bf) {
    return (const void*)((const char*)W + row * (size_t)n * (bf ? 2u : 4u));
}

// dot of one weight row (dtype per flag) with a vector of the SAME dtype
template<int N>
__device__ __forceinline__ float dot_dt(const void* wrow, const void* v, int lane, bool bf) {
    float acc = 0.f;
    if (bf) {
        const u16x8* wp = (const u16x8*)wrow;
        const u16x8* vp = (const u16x8*)v;
        #pragma unroll
        for (int k = 0; k < N / 512; ++k) {
            u16x8 a = wp[lane + 64 * k];
            u16x8 b = vp[lane + 64 * k];
            #pragma unroll
            for (int t = 0; t < 8; ++t) acc += bf2f(a[t]) * bf2f(b[t]);
        }
    } else {
        const f32x8* wp = (const f32x8*)wrow;
        const f32x8* vp = (const f32x8*)v;
        #pragma unroll
        for (int k = 0; k < N / 512; ++k) {
            f32x8 a = wp[lane + 64 * k];
            f32x8 b = vp[lane + 64 * k];
            #pragma unroll
            for (int t = 0; t < 8; ++t) acc += a[t] * b[t];
        }
    }
    return acc;
}

// dot of one weight row (dtype per flag) with an fp32 workspace vector
template<int N>
__device__ __forceinline__ float dot_dt_f32v(const void* wrow, const float* v, int lane, bool bf) {
    float acc = 0.f;
    const f32x8* vp = (const f32x8*)v;
    if (bf) {
        const u16x8* wp = (const u16x8*)wrow;
        #pragma unroll
        for (int k = 0; k < N / 512; ++k) {
            u16x8 a = wp[lane + 64 * k];
            f32x8 b = vp[lane + 64 * k];
            #pragma unroll
            for (int t = 0; t < 8; ++t) acc += bf2f(a[t]) * b[t];
        }
    } else {
        const f32x8* wp = (const f32x8*)wrow;
        #pragma unroll
        for (int k = 0; k < N / 512; ++k) {
            f32x8 a = wp[lane + 64 * k];
            f32x8 b = vp[lane + 64 * k];
            #pragma unroll
            for (int t = 0; t < 8; ++t) acc += a[t] * b[t];
        }
    }
    return acc;
}

// ---------------- dtype probe: bf16 vs fp32, decided from x's bit patterns ----------------
// Even-indexed u16 words: bf16 buffer -> bf16 values of ~N(0,1) (exponent field in a narrow
// band, ~100% hits); fp32 buffer -> low mantissa bits (uniform exponent field, ~19% hits).
__global__ __launch_bounds__(64) void probe_kernel(const void* x, int* flag) {
    const int lane = threadIdx.x;
    const u16* p = (const u16*)x;
    int cnt = 0;
    #pragma unroll
    for (int k = 0; k < 8; ++k) {
        u16 w = p[2 * (lane + 64 * k)];   // max byte offset 2045 < 2048 (safe for bf16 buffer)
        int e = (w >> 7) & 0xFF;
        if (e >= 0x60 && e <= 0x8F) cnt++;
    }
    float c = wave_reduce_sum((float)cnt);
    if (lane == 0) flag[0] = (c > 300.f) ? 1 : 0;
}

// ---------------- LSTM layer 1 ----------------
// grid = H_DIM blocks x 256 thr (4 waves); wave w computes gate-row w*H_DIM + j.
__global__ __launch_bounds__(256) void lstm1_kernel(
    const void* __restrict__ x, const void* __restrict__ h1, const void* __restrict__ c1,
    const void* __restrict__ W_ih, const void* __restrict__ W_hh,
    const void* __restrict__ b_ih, const void* __restrict__ b_hh,
    const int* __restrict__ flag, float* __restrict__ h_out)
{
    const bool bf  = (*flag != 0);
    const int j    = blockIdx.x;
    const int wave = threadIdx.x >> 6;
    const int lane = threadIdx.x & 63;
    const int row  = wave * H_DIM + j;

    float acc = dot_dt<IN_DIM>(row_ptr(W_ih, (size_t)row, IN_DIM, bf), x, lane, bf)
              + dot_dt<H_DIM>(row_ptr(W_hh, (size_t)row, H_DIM, bf), h1, lane, bf);
    acc = wave_reduce_sum(acc);

    __shared__ float gs[4];
    if (lane == 0) gs[wave] = acc + ld_scalar(b_ih, row, bf) + ld_scalar(b_hh, row, bf);
    __syncthreads();
    if (threadIdx.x == 0) {
        float gi = sigmoidf(gs[0]);
        float gf = sigmoidf(gs[1]);
        float gg = tanhf(gs[2]);
        float go = sigmoidf(gs[3]);
        float c  = gf * ld_scalar(c1, j, bf) + gi * gg;
        h_out[j] = go * tanhf(c);
    }
}

// ---------------- LSTM layer 2: input h1n is fp32 in ws ----------------
__global__ __launch_bounds__(256) void lstm2_kernel(
    const float* __restrict__ h1n, const void* __restrict__ h2, const void* __restrict__ c2,
    const void* __restrict__ W_ih, const void* __restrict__ W_hh,
    const void* __restrict__ b_ih, const void* __restrict__ b_hh,
    const int* __restrict__ flag, float* __restrict__ h_out)
{
    const bool bf  = (*flag != 0);
    const int j    = blockIdx.x;
    const int wave = threadIdx.x >> 6;
    const int lane = threadIdx.x & 63;
    const int row  = wave * H_DIM + j;

    float acc = dot_dt_f32v<H_DIM>(row_ptr(W_ih, (size_t)row, H_DIM, bf), h1n, lane, bf)
              + dot_dt<H_DIM>(row_ptr(W_hh, (size_t)row, H_DIM, bf), h2, lane, bf);
    acc = wave_reduce_sum(acc);

    __shared__ float gs[4];
    if (lane == 0) gs[wave] = acc + ld_scalar(b_ih, row, bf) + ld_scalar(b_hh, row, bf);
    __syncthreads();
    if (threadIdx.x == 0) {
        float gi = sigmoidf(gs[0]);
        float gf = sigmoidf(gs[1]);
        float gg = tanhf(gs[2]);
        float go = sigmoidf(gs[3]);
        float c  = gf * ld_scalar(c2, j, bf) + gi * gg;
        h_out[j] = go * tanhf(c);
    }
}

// ---------------- logits + per-block online softmax partials ----------------
#define ROWS_PER_WAVE 8
#define ROWS_PER_BLOCK 32
__global__ __launch_bounds__(256) void logits_kernel(
    const float* __restrict__ h2n, const void* __restrict__ W, const void* __restrict__ b,
    const int* __restrict__ flag,
    float* __restrict__ logits, float* __restrict__ pmax, float* __restrict__ psum)
{
    const bool bf  = (*flag != 0);
    const int wave = threadIdx.x >> 6;
    const int lane = threadIdx.x & 63;

    float hreg[32];
    {
        const f32x8* hv = (const f32x8*)h2n;
        #pragma unroll
        for (int k = 0; k < 4; ++k) {
            f32x8 hh = hv[lane + 64 * k];
            #pragma unroll
            for (int t = 0; t < 8; ++t) hreg[8 * k + t] = hh[t];
        }
    }

    const int base = blockIdx.x * ROWS_PER_BLOCK + wave * ROWS_PER_WAVE;
    float m = NEG_BIG, s = 0.f;
    for (int rr = 0; rr < ROWS_PER_WAVE; ++rr) {
        const int row = base + rr;
        if (row < V_DIM) {
            float acc = 0.f;
            if (bf) {
                const u16x8* wr = (const u16x8*)row_ptr(W, (size_t)row, H_DIM, true);
                #pragma unroll
                for (int k = 0; k < 4; ++k) {
                    u16x8 w = wr[lane + 64 * k];
                    #pragma unroll
                    for (int t = 0; t < 8; ++t) acc += bf2f(w[t]) * hreg[8 * k + t];
                }
            } else {
                const f32x8* wr = (const f32x8*)row_ptr(W, (size_t)row, H_DIM, false);
                #pragma unroll
                for (int k = 0; k < 4; ++k) {
                    f32x8 w = wr[lane + 64 * k];
                    #pragma unroll
                    for (int t = 0; t < 8; ++t) acc += w[t] * hreg[8 * k + t];
                }
            }
            acc = wave_reduce_sum(acc);
            if (lane == 0) {
                float lg = acc + ld_scalar(b, row, bf);
                logits[row] = lg;
                float mn = fmaxf(m, lg);
                s = s * __expf(m - mn) + __expf(lg - mn);
                m = mn;
            }
        }
    }
    __shared__ float wm[4], wsv[4];
    if (lane == 0) { wm[wave] = m; wsv[wave] = s; }
    __syncthreads();
    if (threadIdx.x == 0) {
        float M = fmaxf(fmaxf(wm[0], wm[1]), fmaxf(wm[2], wm[3]));
        float S = 0.f;
        #pragma unroll
        for (int w = 0; w < 4; ++w) S += wsv[w] * __expf(wm[w] - M);  // empty wave: 0*exp(very neg)=0
        pmax[blockIdx.x] = M;
        psum[blockIdx.x] = S;
    }
}

// ---------------- finalize: partials -> logZ; out = (logits - logZ) in flag dtype ----------------
__global__ __launch_bounds__(256) void finalize_kernel(
    const float* __restrict__ logits, const float* __restrict__ pmax,
    const float* __restrict__ psum, int nblk, const int* __restrict__ flag,
    void* __restrict__ out)
{
    const bool bf = (*flag != 0);
    __shared__ float sm[256], ss[256];
    float m = NEG_BIG, s = 0.f;
    for (int i = threadIdx.x; i < nblk; i += 256) {
        float bm = pmax[i], bs = psum[i];
        float mn = fmaxf(m, bm);
        s = s * __expf(m - mn) + bs * __expf(bm - mn);
        m = mn;
    }
    sm[threadIdx.x] = m; ss[threadIdx.x] = s;
    __syncthreads();
    #pragma unroll
    for (int stride = 128; stride > 0; stride >>= 1) {
        if ((int)threadIdx.x < stride) {
            float m1 = sm[threadIdx.x], s1 = ss[threadIdx.x];
            float m2 = sm[threadIdx.x + stride], s2 = ss[threadIdx.x + stride];
            float mn = fmaxf(m1, m2);
            sm[threadIdx.x] = mn;
            ss[threadIdx.x] = s1 * __expf(m1 - mn) + s2 * __expf(m2 - mn);
        }
        __syncthreads();
    }
    const float logZ = sm[0] + __logf(ss[0]);
    const int i = blockIdx.x * 256 + threadIdx.x;
    if (i < V_DIM) {
        float v = logits[i] - logZ;
        if (bf) ((u16*)out)[i] = f2bf(v);
        else    ((float*)out)[i] = v;
    }
}

extern "C" void kernel_launch(void* const* d_in, const int* in_sizes, int n_in,
                              void* d_out, int out_size, void* d_ws, size_t ws_size,
                              hipStream_t stream)
{
    const void* x     = d_in[0];
    const void* h1    = d_in[1];
    const void* c1    = d_in[2];
    const void* h2    = d_in[3];
    const void* c2    = d_in[4];
    const void* W_ih1 = d_in[5];
    const void* W_hh1 = d_in[6];
    const void* b_ih1 = d_in[7];
    const void* b_hh1 = d_in[8];
    const void* W_ih2 = d_in[9];
    const void* W_hh2 = d_in[10];
    const void* b_ih2 = d_in[11];
    const void* b_hh2 = d_in[12];
    const void* W_out = d_in[13];
    const void* b_out = d_in[14];

    float* ws     = (float*)d_ws;
    float* h1n    = ws;                    // 2048 fp32
    float* h2n    = ws + 2048;             // 2048 fp32
    float* logits = ws + 4096;             // 50257 fp32 (padded to 50264)
    float* pmax   = ws + 4096 + 50264;     // 1571 fp32 (padded to 1576)
    float* psum   = pmax + 1576;           // 1571 fp32 (padded to 1576)
    int*   flag   = (int*)(psum + 1576);   // 1 int

    const int nblk3 = (V_DIM + ROWS_PER_BLOCK - 1) / ROWS_PER_BLOCK;  // 1571

    probe_kernel<<<1, 64, 0, stream>>>(x, flag);
    lstm1_kernel<<<H_DIM, 256, 0, stream>>>(x, h1, c1, W_ih1, W_hh1, b_ih1, b_hh1, flag, h1n);
    lstm2_kernel<<<H_DIM, 256, 0, stream>>>(h1n, h2, c2, W_ih2, W_hh2, b_ih2, b_hh2, flag, h2n);
    logits_kernel<<<nblk3, 256, 0, stream>>>(h2n, W_out, b_out, flag, logits, pmax, psum);
    finalize_kernel<<<(V_DIM + 255) / 256, 256, 0, stream>>>(logits, pmax, psum, nblk3, flag, d_out);
}